// Round 2
// 327.719 us; speedup vs baseline: 1.2592x; 1.2592x over previous
//
#include <hip/hip_runtime.h>

// JaggedConv2D via banded-Toeplitz MFMA (mfma_f32_16x16x32_f16).
// x: (4,128,256,256) f32, kernels: (128,1,29,29) f32 (pre-masked ragged),
// out: (4,128,256,256) f32.
//
// D[m][n] (16x16) = out rows x cols. K = 32 input columns per strip.
// A = input data from LDS (row-major, 16B/lane ds_read_b128).
// B = Toeplitz weights  B[k][n] = w[dy][k-n+s]  (0 off-band), prepacked
//     per (c,dy,strip) into d_ws as 64 lanes x 4 u32, loaded coalesced.
// Per dy: kk<=17 -> 1 strip (4 MFMA / wave), kk>17 -> 2 strips (8 MFMA),
// with A-fragment sharing across strips (strip1 tile t == strip0 tile t+2).

#define C_CH   128
#define HW     256
#define KMAX   29
#define TILE   64
#define ROWH   120            // LDS row stride in halves (240 B = 15 x 16B chunks, odd)
#define ROWU   60             // row stride in u32
#define STAGE_W 56            // staged u32 per row (112 halves)
#define MAXR   92             // max staged rows (64 + 29 - 1)

typedef __fp16 f16x8 __attribute__((ext_vector_type(8)));
typedef float  f32x4 __attribute__((ext_vector_type(4)));
typedef __fp16 half2_t __attribute__((ext_vector_type(2)));

__device__ __forceinline__ unsigned pack_f16(float a, float b) {
    half2_t h = __builtin_amdgcn_cvt_pkrtz(a, b);
    union { half2_t h; unsigned u; } cvt; cvt.h = h; return cvt.u;
}
__device__ __forceinline__ f16x8 uint4_as_f16x8(uint4 v) {
    union { uint4 u; f16x8 h; } cvt; cvt.u = v; return cvt.h;
}
__device__ __forceinline__ half2_t u32_as_h2(unsigned u) {
    union { unsigned u; half2_t h; } cvt; cvt.u = u; return cvt.h;
}
__device__ __forceinline__ int ragged_k(int c) {
    int kk = (int)(5.0 + 24.0 * (double)c / 127.0);
    kk -= (1 - (kk & 1));     // force odd (matches linspace->int64->odd in ref)
    return kk;
}

// ---------- Toeplitz fragment prepack: ws[(c*29+dy)*2+strip][lane] = 4 u32 ----
__global__ __launch_bounds__(128)
void prepack_frags(const float* __restrict__ kern, uint4* __restrict__ wf)
{
    const int c   = blockIdx.x;        // 128
    const int dy  = blockIdx.y;        // 29
    const int tid = threadIdx.x;       // 2 strips x 64 lanes
    const int strip = tid >> 6;
    const int lane  = tid & 63;
    const int kk = ragged_k(c);
    const int s  = (KMAX - kk) >> 1;
    const int n  = lane & 15;          // B col (output x within 16-tile)
    const int kb = lane >> 4;          // k block: lane holds k = strip*32 + kb*8 + j
    const float* wrow = kern + c * (KMAX * KMAX) + dy * KMAX;
    unsigned u[4];
    #pragma unroll
    for (int r = 0; r < 4; ++r) {
        float v[2];
        #pragma unroll
        for (int h = 0; h < 2; ++h) {
            const int k = strip * 32 + kb * 8 + 2 * r + h;
            const int d = k - n;                       // dx - s
            v[h] = (d >= 0 && d < kk) ? wrow[d + s] : 0.0f;
        }
        u[r] = pack_f16(v[0], v[1]);
    }
    wf[(size_t)((c * KMAX + dy) * 2 + strip) * 64 + lane] =
        make_uint4(u[0], u[1], u[2], u[3]);
}

// ---------------------------- MFMA main conv -------------------------------
__global__ __launch_bounds__(256, 4)
void jagged_conv_mfma(const float* __restrict__ x,
                      const uint4* __restrict__ wf,
                      float* __restrict__ out)
{
    const int bx = blockIdx.x;
    const int by = blockIdx.y;
    const int bc = blockIdx.z;
    const int c  = bc & (C_CH - 1);
    const int kk = ragged_k(c);
    const int s  = (KMAX - kk) >> 1;
    const int R  = TILE + kk - 1;      // staged input rows

    __shared__ __align__(16) unsigned tile[MAXR * ROWU];   // f16 pairs, 22 KB

    const int tid = threadIdx.x;
    const int rbase = by * TILE + s - 14;   // first staged input row
    const int cbase = bx * TILE + s - 14;   // first staged input col
    const float* xin = x + (size_t)bc * (HW * HW);

    // ---- stage input tile+halo as packed f16 (zero outside image) ----
    for (int i = tid; i < R * STAGE_W; i += 256) {
        const int r = i / STAGE_W;
        const int p = i - r * STAGE_W;
        const int gy = rbase + r;
        const int gx = cbase + 2 * p;
        float a = 0.0f, b = 0.0f;
        if ((unsigned)gy < HW) {
            const float* row = xin + gy * HW;
            if ((unsigned)gx < HW)       a = row[gx];
            if ((unsigned)(gx + 1) < HW) b = row[gx + 1];
        }
        tile[r * ROWU + p] = pack_f16(a, b);
    }
    __syncthreads();

    const int lane = tid & 63;
    const int w    = tid >> 6;         // wave: 16-row band of the 64x64 tile
    const int ml   = lane & 15;        // A-row index m
    const int kb   = lane >> 4;        // k block

    f32x4 acc0 = {0,0,0,0}, acc1 = {0,0,0,0}, acc2 = {0,0,0,0}, acc3 = {0,0,0,0};

    const __fp16* hp = (const __fp16*)tile;
    // lane's A base: tile row (16w + ml + d), col 8*kb  (all 16B aligned)
    const __fp16* abase = hp + (16 * w + ml) * ROWH + 8 * kb;
    const uint4* wfc = wf + (size_t)c * (KMAX * 2 * 64) + lane;

    const bool two = (kk > 17);        // block-uniform
    for (int d = 0; d < kk; ++d) {     // d = dy - s
        const int dy = s + d;
        const __fp16* ap = abase + d * ROWH;
        f16x8 F0 = *(const f16x8*)(ap);
        f16x8 F1 = *(const f16x8*)(ap + 16);
        f16x8 F2 = *(const f16x8*)(ap + 32);
        f16x8 F3 = *(const f16x8*)(ap + 48);
        uint4 b0 = wfc[(size_t)(dy * 2 + 0) * 64];
        f16x8 B0 = uint4_as_f16x8(b0);
        acc0 = __builtin_amdgcn_mfma_f32_16x16x32_f16(F0, B0, acc0, 0, 0, 0);
        acc1 = __builtin_amdgcn_mfma_f32_16x16x32_f16(F1, B0, acc1, 0, 0, 0);
        acc2 = __builtin_amdgcn_mfma_f32_16x16x32_f16(F2, B0, acc2, 0, 0, 0);
        acc3 = __builtin_amdgcn_mfma_f32_16x16x32_f16(F3, B0, acc3, 0, 0, 0);
        if (two) {
            f16x8 F4 = *(const f16x8*)(ap + 64);
            f16x8 F5 = *(const f16x8*)(ap + 80);
            uint4 b1 = wfc[(size_t)(dy * 2 + 1) * 64];
            f16x8 B1 = uint4_as_f16x8(b1);
            acc0 = __builtin_amdgcn_mfma_f32_16x16x32_f16(F2, B1, acc0, 0, 0, 0);
            acc1 = __builtin_amdgcn_mfma_f32_16x16x32_f16(F3, B1, acc1, 0, 0, 0);
            acc2 = __builtin_amdgcn_mfma_f32_16x16x32_f16(F4, B1, acc2, 0, 0, 0);
            acc3 = __builtin_amdgcn_mfma_f32_16x16x32_f16(F5, B1, acc3, 0, 0, 0);
        }
    }

    // D layout: col = lane&15 (=ml), row = kb*4 + reg
    float* op = out + (size_t)bc * (HW * HW)
              + (size_t)(by * TILE + 16 * w + kb * 4) * HW
              + bx * TILE + ml;
    #pragma unroll
    for (int r = 0; r < 4; ++r) {
        op[r * HW + 0]  = acc0[r];
        op[r * HW + 16] = acc1[r];
        op[r * HW + 32] = acc2[r];
        op[r * HW + 48] = acc3[r];
    }
}

// ======================= fallback: previous fdot2 kernel ====================
#define PAD    14
#define LDS_R  92
#define ROW_U32 52

__global__ __launch_bounds__(512)
void prepack_weights(const float* __restrict__ kern, unsigned* __restrict__ wp)
{
    const int c = blockIdx.x;
    const int tid = threadIdx.x;
    if (tid >= 29 * 16) return;
    const int dy = tid >> 4;
    const int t  = tid & 15;
    float w0 = 0.0f, w1 = 0.0f;
    if (2 * t < KMAX)     w0 = kern[c * (KMAX * KMAX) + dy * KMAX + 2 * t];
    if (2 * t + 1 < KMAX) w1 = kern[c * (KMAX * KMAX) + dy * KMAX + 2 * t + 1];
    wp[(c * KMAX + dy) * 16 + t] = pack_f16(w0, w1);
}

__global__ __launch_bounds__(256, 4)
void jagged_conv_kernel(const float* __restrict__ x,
                        const unsigned* __restrict__ wp,
                        float* __restrict__ out)
{
    const int bx = blockIdx.x;
    const int by = blockIdx.y;
    const int bc = blockIdx.z;
    const int c  = bc & (C_CH - 1);

    int kk = ragged_k(c);
    const int s  = (KMAX - kk) >> 1;
    const int t0 = s >> 1;
    const int t1 = (s + kk - 1) >> 1;

    __shared__ __align__(16) unsigned tile[LDS_R * ROW_U32];

    const int tid = threadIdx.x;
    const int gy0 = by * TILE - PAD;
    const int gx0 = bx * TILE - PAD;
    const float* xin = x + (size_t)bc * (HW * HW);

    for (int i = tid; i < LDS_R * ROW_U32; i += 256) {
        const int r = i / ROW_U32;
        const int p = i - r * ROW_U32;
        const int gy = gy0 + r;
        const int gx = gx0 + 2 * p;
        float a = 0.0f, b = 0.0f;
        if ((unsigned)gy < HW) {
            const float* row = xin + gy * HW;
            if ((unsigned)gx < HW)       a = row[gx];
            if ((unsigned)(gx + 1) < HW) b = row[gx + 1];
        }
        tile[i] = pack_f16(a, b);
    }
    __syncthreads();

    const int tx = tid & 7;
    const int ty = tid >> 3;

    float acc[2][8];
    #pragma unroll
    for (int j = 0; j < 2; ++j)
        #pragma unroll
        for (int p = 0; p < 8; ++p) acc[j][p] = 0.0f;

    const unsigned* wch = wp + c * (KMAX * 16);

    const int rend = s + kk + 1;
    for (int rr = s; rr < rend; ++rr) {
        const uint4* lp = (const uint4*)&tile[(ty * 2 + rr) * ROW_U32 + tx * 4];
        unsigned seg[20];
        {
            uint4 v0 = lp[0], v1 = lp[1], v2 = lp[2], v3 = lp[3], v4 = lp[4];
            seg[0]=v0.x; seg[1]=v0.y; seg[2]=v0.z; seg[3]=v0.w;
            seg[4]=v1.x; seg[5]=v1.y; seg[6]=v1.z; seg[7]=v1.w;
            seg[8]=v2.x; seg[9]=v2.y; seg[10]=v2.z; seg[11]=v2.w;
            seg[12]=v3.x; seg[13]=v3.y; seg[14]=v3.z; seg[15]=v3.w;
            seg[16]=v4.x; seg[17]=v4.y; seg[18]=v4.z; seg[19]=v4.w;
        }
        unsigned sseg[18];
        #pragma unroll
        for (int k = 0; k < 18; ++k)
            sseg[k] = __builtin_amdgcn_alignbit(seg[k + 1], seg[k], 16);

        #pragma unroll
        for (int j = 0; j < 2; ++j) {
            const int dy = rr - j;
            if (dy >= s && dy < s + kk) {
                const unsigned* wrow = wch + dy * 16;
                unsigned wv[16];
                #pragma unroll
                for (int t = 0; t < 16; ++t) wv[t] = wrow[t];
                #pragma unroll
                for (int t = 0; t < 15; ++t) {
                    if (t >= t0 && t <= t1) {
                        const half2_t wh = u32_as_h2(wv[t]);
                        acc[j][0] = __builtin_amdgcn_fdot2(u32_as_h2(seg[t + 0]), wh, acc[j][0], false);
                        acc[j][2] = __builtin_amdgcn_fdot2(u32_as_h2(seg[t + 1]), wh, acc[j][2], false);
                        acc[j][4] = __builtin_amdgcn_fdot2(u32_as_h2(seg[t + 2]), wh, acc[j][4], false);
                        acc[j][6] = __builtin_amdgcn_fdot2(u32_as_h2(seg[t + 3]), wh, acc[j][6], false);
                        acc[j][1] = __builtin_amdgcn_fdot2(u32_as_h2(sseg[t + 0]), wh, acc[j][1], false);
                        acc[j][3] = __builtin_amdgcn_fdot2(u32_as_h2(sseg[t + 1]), wh, acc[j][3], false);
                        acc[j][5] = __builtin_amdgcn_fdot2(u32_as_h2(sseg[t + 2]), wh, acc[j][5], false);
                        acc[j][7] = __builtin_amdgcn_fdot2(u32_as_h2(sseg[t + 3]), wh, acc[j][7], false);
                    }
                }
            }
        }
    }

    float* op = out + (size_t)bc * (HW * HW);
    const int ox = bx * TILE + tx * 8;
    #pragma unroll
    for (int j = 0; j < 2; ++j) {
        const int oy = by * TILE + ty * 2 + j;
        float4 o0 = make_float4(acc[j][0], acc[j][1], acc[j][2], acc[j][3]);
        float4 o1 = make_float4(acc[j][4], acc[j][5], acc[j][6], acc[j][7]);
        *(float4*)(op + (size_t)oy * HW + ox)     = o0;
        *(float4*)(op + (size_t)oy * HW + ox + 4) = o1;
    }
}

// ---------------------------------------------------------------------------
extern "C" void kernel_launch(void* const* d_in, const int* in_sizes, int n_in,
                              void* d_out, int out_size, void* d_ws, size_t ws_size,
                              hipStream_t stream) {
    const float* x    = (const float*)d_in[0];
    const float* kern = (const float*)d_in[1];
    float* out        = (float*)d_out;

    const size_t WF_BYTES = (size_t)C_CH * KMAX * 2 * 64 * 16;   // 7,602,176 B

    if (ws_size >= WF_BYTES) {
        uint4* wf = (uint4*)d_ws;
        prepack_frags<<<dim3(C_CH, KMAX), dim3(128), 0, stream>>>(kern, wf);
        dim3 grid(HW / TILE, HW / TILE, 4 * C_CH);               // 4 x 4 x 512
        jagged_conv_mfma<<<grid, dim3(256), 0, stream>>>(x, wf, out);
    } else {
        // fallback: previous fdot2 kernel (needs only 237,568 B of ws)
        unsigned* wpack = (unsigned*)d_ws;
        prepack_weights<<<dim3(C_CH), dim3(512), 0, stream>>>(kern, wpack);
        dim3 grid(HW / TILE, HW / TILE, 4 * C_CH);
        jagged_conv_kernel<<<grid, dim3(256), 0, stream>>>(x, wpack, out);
    }
}

// Round 3
// 324.235 us; speedup vs baseline: 1.2727x; 1.0107x over previous
//
#include <hip/hip_runtime.h>

// JaggedConv2D via banded-Toeplitz MFMA (mfma_f32_16x16x32_f16), v2.
// x: (4,128,256,256) f32, kernels: (128,1,29,29) f32 (pre-masked ragged),
// out: (4,128,256,256) f32.
//
// v2 changes vs v1 (169 us conv dispatch, latency-bound, nothing saturated):
//  - block tile 128x64, wave = 16 rows x 128 cols -> one B fragment feeds
//    8 MFMAs (was 4): wf L2 traffic halved, ds_read/MFMA 0.75 -> 0.625.
//  - 1-deep software prefetch of next-d B fragments (hides ~200cy L2 lat).
//  - LDS row stride 184 halves = 23 quads (odd) -> even bank-quad spread.

#define C_CH    128
#define HW      256
#define KMAX    29
#define TILE_W  128
#define TILE_H  64
#define ROWH    184           // LDS row stride in halves (368 B = 23 x 16B, odd)
#define ROWU    92            // row stride in u32
#define STAGE_W 88            // staged u32 per row (176 halves, covers F9 kb=3)
#define MAXR    92            // max staged rows (64 + 29 - 1)

typedef __fp16 f16x8 __attribute__((ext_vector_type(8)));
typedef float  f32x4 __attribute__((ext_vector_type(4)));
typedef __fp16 half2_t __attribute__((ext_vector_type(2)));

__device__ __forceinline__ unsigned pack_f16(float a, float b) {
    half2_t h = __builtin_amdgcn_cvt_pkrtz(a, b);
    union { half2_t h; unsigned u; } cvt; cvt.h = h; return cvt.u;
}
__device__ __forceinline__ f16x8 uint4_as_f16x8(uint4 v) {
    union { uint4 u; f16x8 h; } cvt; cvt.u = v; return cvt.h;
}
__device__ __forceinline__ half2_t u32_as_h2(unsigned u) {
    union { unsigned u; half2_t h; } cvt; cvt.u = u; return cvt.h;
}
__device__ __forceinline__ int ragged_k(int c) {
    int kk = (int)(5.0 + 24.0 * (double)c / 127.0);
    kk -= (1 - (kk & 1));     // force odd (matches linspace->int64->odd in ref)
    return kk;
}

// ---------- Toeplitz fragment prepack: ws[(c*29+dy)*2+strip][lane] = 4 u32 ----
// B[k][n] = w[dy][32*strip + k - n + s] (0 off-band). Unchanged from v1.
__global__ __launch_bounds__(128)
void prepack_frags(const float* __restrict__ kern, uint4* __restrict__ wf)
{
    const int c   = blockIdx.x;        // 128
    const int dy  = blockIdx.y;        // 29
    const int tid = threadIdx.x;       // 2 strips x 64 lanes
    const int strip = tid >> 6;
    const int lane  = tid & 63;
    const int kk = ragged_k(c);
    const int s  = (KMAX - kk) >> 1;
    const int n  = lane & 15;          // B col (output x within 16-tile)
    const int kb = lane >> 4;          // k block: lane holds k = strip*32 + kb*8 + j
    const float* wrow = kern + c * (KMAX * KMAX) + dy * KMAX;
    unsigned u[4];
    #pragma unroll
    for (int r = 0; r < 4; ++r) {
        float v[2];
        #pragma unroll
        for (int h = 0; h < 2; ++h) {
            const int k = strip * 32 + kb * 8 + 2 * r + h;
            const int d = k - n;                       // dx - s
            v[h] = (d >= 0 && d < kk) ? wrow[d + s] : 0.0f;
        }
        u[r] = pack_f16(v[0], v[1]);
    }
    wf[(size_t)((c * KMAX + dy) * 2 + strip) * 64 + lane] =
        make_uint4(u[0], u[1], u[2], u[3]);
}

// ---------------------------- MFMA main conv -------------------------------
__global__ __launch_bounds__(256, 4)
void jagged_conv_mfma(const float* __restrict__ x,
                      const uint4* __restrict__ wf,
                      float* __restrict__ out)
{
    const int bx = blockIdx.x;         // 0..1   (128-wide tiles)
    const int by = blockIdx.y;         // 0..3   (64-tall tiles)
    const int bc = blockIdx.z;         // 0..511
    const int c  = bc & (C_CH - 1);
    const int kk = ragged_k(c);
    const int s  = (KMAX - kk) >> 1;
    const int R  = TILE_H + kk - 1;    // staged input rows

    __shared__ __align__(16) unsigned tile[MAXR * ROWU];   // f16 pairs, 33.9 KB

    const int tid = threadIdx.x;
    const int rbase = by * TILE_H + s - 14;   // first staged input row
    const int cbase = bx * TILE_W + s - 14;   // first staged input col
    const float* xin = x + (size_t)bc * (HW * HW);

    // ---- stage input tile+halo as packed f16 (zero outside image) ----
    for (int i = tid; i < R * STAGE_W; i += 256) {
        const int r = i / STAGE_W;
        const int p = i - r * STAGE_W;
        const int gy = rbase + r;
        const int gx = cbase + 2 * p;
        float a = 0.0f, b = 0.0f;
        if ((unsigned)gy < HW) {
            const float* row = xin + gy * HW;
            if ((unsigned)gx < HW)       a = row[gx];
            if ((unsigned)(gx + 1) < HW) b = row[gx + 1];
        }
        tile[r * ROWU + p] = pack_f16(a, b);
    }
    __syncthreads();

    const int lane = tid & 63;
    const int w    = tid >> 6;         // wave: 16-row band of the 64-row tile
    const int ml   = lane & 15;        // A row (m) and D col
    const int kb   = lane >> 4;        // k block; D row = 4*kb + reg

    f32x4 a0 = {0,0,0,0}, a1 = {0,0,0,0}, a2 = {0,0,0,0}, a3 = {0,0,0,0};
    f32x4 a4 = {0,0,0,0}, a5 = {0,0,0,0}, a6 = {0,0,0,0}, a7 = {0,0,0,0};

    const __fp16* hp = (const __fp16*)tile;
    // lane's A base: tile row (16w + ml + d), halves col 16t + 32*strip + 8kb
    const __fp16* ap = hp + (16 * w + ml) * ROWH + 8 * kb;
    const uint4* wp = wf + (size_t)c * (KMAX * 2 * 64) + (size_t)(2 * s) * 64 + lane;

    const bool two = (kk > 17);        // block-uniform

    uint4 nb0 = wp[0];
    uint4 nb1 = two ? wp[64] : nb0;

    for (int d = 0; d < kk; ++d) {
        const uint4 b0 = nb0;
        const uint4 b1 = nb1;
        wp += 128;
        if (d + 1 < kk) {              // prefetch next dy's fragments
            nb0 = wp[0];
            if (two) nb1 = wp[64];
        }

        f16x8 F0 = *(const f16x8*)(ap +   0);
        f16x8 F1 = *(const f16x8*)(ap +  16);
        f16x8 F2 = *(const f16x8*)(ap +  32);
        f16x8 F3 = *(const f16x8*)(ap +  48);
        f16x8 F4 = *(const f16x8*)(ap +  64);
        f16x8 F5 = *(const f16x8*)(ap +  80);
        f16x8 F6 = *(const f16x8*)(ap +  96);
        f16x8 F7 = *(const f16x8*)(ap + 112);

        f16x8 B0 = uint4_as_f16x8(b0);
        a0 = __builtin_amdgcn_mfma_f32_16x16x32_f16(F0, B0, a0, 0, 0, 0);
        a1 = __builtin_amdgcn_mfma_f32_16x16x32_f16(F1, B0, a1, 0, 0, 0);
        a2 = __builtin_amdgcn_mfma_f32_16x16x32_f16(F2, B0, a2, 0, 0, 0);
        a3 = __builtin_amdgcn_mfma_f32_16x16x32_f16(F3, B0, a3, 0, 0, 0);
        a4 = __builtin_amdgcn_mfma_f32_16x16x32_f16(F4, B0, a4, 0, 0, 0);
        a5 = __builtin_amdgcn_mfma_f32_16x16x32_f16(F5, B0, a5, 0, 0, 0);
        a6 = __builtin_amdgcn_mfma_f32_16x16x32_f16(F6, B0, a6, 0, 0, 0);
        a7 = __builtin_amdgcn_mfma_f32_16x16x32_f16(F7, B0, a7, 0, 0, 0);

        if (two) {
            f16x8 F8 = *(const f16x8*)(ap + 128);
            f16x8 F9 = *(const f16x8*)(ap + 144);
            f16x8 B1 = uint4_as_f16x8(b1);
            a0 = __builtin_amdgcn_mfma_f32_16x16x32_f16(F2, B1, a0, 0, 0, 0);
            a1 = __builtin_amdgcn_mfma_f32_16x16x32_f16(F3, B1, a1, 0, 0, 0);
            a2 = __builtin_amdgcn_mfma_f32_16x16x32_f16(F4, B1, a2, 0, 0, 0);
            a3 = __builtin_amdgcn_mfma_f32_16x16x32_f16(F5, B1, a3, 0, 0, 0);
            a4 = __builtin_amdgcn_mfma_f32_16x16x32_f16(F6, B1, a4, 0, 0, 0);
            a5 = __builtin_amdgcn_mfma_f32_16x16x32_f16(F7, B1, a5, 0, 0, 0);
            a6 = __builtin_amdgcn_mfma_f32_16x16x32_f16(F8, B1, a6, 0, 0, 0);
            a7 = __builtin_amdgcn_mfma_f32_16x16x32_f16(F9, B1, a7, 0, 0, 0);
        }
        ap += ROWH;
    }

    // D layout: col = lane&15 (=ml), row = kb*4 + reg
    float* op = out + (size_t)bc * (HW * HW)
              + (size_t)(by * TILE_H + 16 * w + 4 * kb) * HW
              + bx * TILE_W + ml;
    #pragma unroll
    for (int r = 0; r < 4; ++r) {
        op[r * HW +   0] = a0[r];
        op[r * HW +  16] = a1[r];
        op[r * HW +  32] = a2[r];
        op[r * HW +  48] = a3[r];
        op[r * HW +  64] = a4[r];
        op[r * HW +  80] = a5[r];
        op[r * HW +  96] = a6[r];
        op[r * HW + 112] = a7[r];
    }
}

// ======================= fallback: fdot2 kernel (64-tile) ===================
#define FB_TILE 64
#define PAD     14
#define LDS_R   92
#define ROW_U32 52

__global__ __launch_bounds__(512)
void prepack_weights(const float* __restrict__ kern, unsigned* __restrict__ wp)
{
    const int c = blockIdx.x;
    const int tid = threadIdx.x;
    if (tid >= 29 * 16) return;
    const int dy = tid >> 4;
    const int t  = tid & 15;
    float w0 = 0.0f, w1 = 0.0f;
    if (2 * t < KMAX)     w0 = kern[c * (KMAX * KMAX) + dy * KMAX + 2 * t];
    if (2 * t + 1 < KMAX) w1 = kern[c * (KMAX * KMAX) + dy * KMAX + 2 * t + 1];
    wp[(c * KMAX + dy) * 16 + t] = pack_f16(w0, w1);
}

__global__ __launch_bounds__(256, 4)
void jagged_conv_kernel(const float* __restrict__ x,
                        const unsigned* __restrict__ wp,
                        float* __restrict__ out)
{
    const int bx = blockIdx.x;
    const int by = blockIdx.y;
    const int bc = blockIdx.z;
    const int c  = bc & (C_CH - 1);

    int kk = ragged_k(c);
    const int s  = (KMAX - kk) >> 1;
    const int t0 = s >> 1;
    const int t1 = (s + kk - 1) >> 1;

    __shared__ __align__(16) unsigned tile[LDS_R * ROW_U32];

    const int tid = threadIdx.x;
    const int gy0 = by * FB_TILE - PAD;
    const int gx0 = bx * FB_TILE - PAD;
    const float* xin = x + (size_t)bc * (HW * HW);

    for (int i = tid; i < LDS_R * ROW_U32; i += 256) {
        const int r = i / ROW_U32;
        const int p = i - r * ROW_U32;
        const int gy = gy0 + r;
        const int gx = gx0 + 2 * p;
        float a = 0.0f, b = 0.0f;
        if ((unsigned)gy < HW) {
            const float* row = xin + gy * HW;
            if ((unsigned)gx < HW)       a = row[gx];
            if ((unsigned)(gx + 1) < HW) b = row[gx + 1];
        }
        tile[i] = pack_f16(a, b);
    }
    __syncthreads();

    const int tx = tid & 7;
    const int ty = tid >> 3;

    float acc[2][8];
    #pragma unroll
    for (int j = 0; j < 2; ++j)
        #pragma unroll
        for (int p = 0; p < 8; ++p) acc[j][p] = 0.0f;

    const unsigned* wch = wp + c * (KMAX * 16);

    const int rend = s + kk + 1;
    for (int rr = s; rr < rend; ++rr) {
        const uint4* lp = (const uint4*)&tile[(ty * 2 + rr) * ROW_U32 + tx * 4];
        unsigned seg[20];
        {
            uint4 v0 = lp[0], v1 = lp[1], v2 = lp[2], v3 = lp[3], v4 = lp[4];
            seg[0]=v0.x; seg[1]=v0.y; seg[2]=v0.z; seg[3]=v0.w;
            seg[4]=v1.x; seg[5]=v1.y; seg[6]=v1.z; seg[7]=v1.w;
            seg[8]=v2.x; seg[9]=v2.y; seg[10]=v2.z; seg[11]=v2.w;
            seg[12]=v3.x; seg[13]=v3.y; seg[14]=v3.z; seg[15]=v3.w;
            seg[16]=v4.x; seg[17]=v4.y; seg[18]=v4.z; seg[19]=v4.w;
        }
        unsigned sseg[18];
        #pragma unroll
        for (int k = 0; k < 18; ++k)
            sseg[k] = __builtin_amdgcn_alignbit(seg[k + 1], seg[k], 16);

        #pragma unroll
        for (int j = 0; j < 2; ++j) {
            const int dy = rr - j;
            if (dy >= s && dy < s + kk) {
                const unsigned* wrow = wch + dy * 16;
                unsigned wv[16];
                #pragma unroll
                for (int t = 0; t < 16; ++t) wv[t] = wrow[t];
                #pragma unroll
                for (int t = 0; t < 15; ++t) {
                    if (t >= t0 && t <= t1) {
                        const half2_t wh = u32_as_h2(wv[t]);
                        acc[j][0] = __builtin_amdgcn_fdot2(u32_as_h2(seg[t + 0]), wh, acc[j][0], false);
                        acc[j][2] = __builtin_amdgcn_fdot2(u32_as_h2(seg[t + 1]), wh, acc[j][2], false);
                        acc[j][4] = __builtin_amdgcn_fdot2(u32_as_h2(seg[t + 2]), wh, acc[j][4], false);
                        acc[j][6] = __builtin_amdgcn_fdot2(u32_as_h2(seg[t + 3]), wh, acc[j][6], false);
                        acc[j][1] = __builtin_amdgcn_fdot2(u32_as_h2(sseg[t + 0]), wh, acc[j][1], false);
                        acc[j][3] = __builtin_amdgcn_fdot2(u32_as_h2(sseg[t + 1]), wh, acc[j][3], false);
                        acc[j][5] = __builtin_amdgcn_fdot2(u32_as_h2(sseg[t + 2]), wh, acc[j][5], false);
                        acc[j][7] = __builtin_amdgcn_fdot2(u32_as_h2(sseg[t + 3]), wh, acc[j][7], false);
                    }
                }
            }
        }
    }

    float* op = out + (size_t)bc * (HW * HW);
    const int ox = bx * FB_TILE + tx * 8;
    #pragma unroll
    for (int j = 0; j < 2; ++j) {
        const int oy = by * FB_TILE + ty * 2 + j;
        float4 o0 = make_float4(acc[j][0], acc[j][1], acc[j][2], acc[j][3]);
        float4 o1 = make_float4(acc[j][4], acc[j][5], acc[j][6], acc[j][7]);
        *(float4*)(op + (size_t)oy * HW + ox)     = o0;
        *(float4*)(op + (size_t)oy * HW + ox + 4) = o1;
    }
}

// ---------------------------------------------------------------------------
extern "C" void kernel_launch(void* const* d_in, const int* in_sizes, int n_in,
                              void* d_out, int out_size, void* d_ws, size_t ws_size,
                              hipStream_t stream) {
    const float* x    = (const float*)d_in[0];
    const float* kern = (const float*)d_in[1];
    float* out        = (float*)d_out;

    const size_t WF_BYTES = (size_t)C_CH * KMAX * 2 * 64 * 16;   // 7,602,176 B

    if (ws_size >= WF_BYTES) {
        uint4* wf = (uint4*)d_ws;
        prepack_frags<<<dim3(C_CH, KMAX), dim3(128), 0, stream>>>(kern, wf);
        dim3 grid(HW / TILE_W, HW / TILE_H, 4 * C_CH);           // 2 x 4 x 512
        jagged_conv_mfma<<<grid, dim3(256), 0, stream>>>(x, wf, out);
    } else {
        // fallback: fdot2 kernel (needs only 237,568 B of ws)
        unsigned* wpack = (unsigned*)d_ws;
        prepack_weights<<<dim3(C_CH), dim3(512), 0, stream>>>(kern, wpack);
        dim3 grid(HW / FB_TILE, HW / FB_TILE, 4 * C_CH);
        jagged_conv_kernel<<<grid, dim3(256), 0, stream>>>(x, wpack, out);
    }
}

// Round 4
// 306.726 us; speedup vs baseline: 1.3454x; 1.0571x over previous
//
#include <hip/hip_runtime.h>

// JaggedConv2D via banded-Toeplitz MFMA (mfma_f32_16x16x32_f16), v3.
// x: (4,128,256,256) f32, kernels: (128,1,29,29) f32 (pre-masked ragged),
// out: (4,128,256,256) f32.
//
// v3 changes vs v2 (165 us conv dispatch, latency-bound, staging serial):
//  - float4 staging, one row per wave per pass, no integer division,
//    ds_write_b64. Staging origin aligned to 8 floats via e=(s+2)&7 shift,
//    which is baked into the Toeplitz prepack (d -= e).
//  - XCD-aware bijective block swizzle: all 8 spatial blocks of one (b,c)
//    slice land on one XCD -> halo + wf reads become L2 hits.
//  - compute loop identical to v2 (verified).

#define C_CH    128
#define HW      256
#define KMAX    29
#define TILE_W  128
#define TILE_H  64
#define ROWH    184           // LDS row stride in halves (368 B = 23 x 16B, odd)
#define ROWU    92            // row stride in u32
#define MAXR    92            // max staged rows (64 + 29 - 1)
#define WQ      44            // staged float4 per row (176 halves)

typedef __fp16 f16x8 __attribute__((ext_vector_type(8)));
typedef float  f32x4 __attribute__((ext_vector_type(4)));
typedef __fp16 half2_t __attribute__((ext_vector_type(2)));

__device__ __forceinline__ unsigned pack_f16(float a, float b) {
    half2_t h = __builtin_amdgcn_cvt_pkrtz(a, b);
    union { half2_t h; unsigned u; } cvt; cvt.h = h; return cvt.u;
}
__device__ __forceinline__ f16x8 uint4_as_f16x8(uint4 v) {
    union { uint4 u; f16x8 h; } cvt; cvt.u = v; return cvt.h;
}
__device__ __forceinline__ half2_t u32_as_h2(unsigned u) {
    union { unsigned u; half2_t h; } cvt; cvt.u = u; return cvt.h;
}
__device__ __forceinline__ int ragged_k(int c) {
    int kk = (int)(5.0 + 24.0 * (double)c / 127.0);
    kk -= (1 - (kk & 1));     // force odd (matches linspace->int64->odd in ref)
    return kk;
}

// ---------- Toeplitz fragment prepack: ws[(c*29+dy)*2+strip][lane] = 4 u32 ----
// LDS col h <-> global col galign + h, galign = bx*128 + s - 14 - e.
// B[k''][n] = w[dy][32*strip + k'' - n - e + s] (0 off-band).
__global__ __launch_bounds__(128)
void prepack_frags(const float* __restrict__ kern, uint4* __restrict__ wf)
{
    const int c   = blockIdx.x;        // 128
    const int dy  = blockIdx.y;        // 29
    const int tid = threadIdx.x;       // 2 strips x 64 lanes
    const int strip = tid >> 6;
    const int lane  = tid & 63;
    const int kk = ragged_k(c);
    const int s  = (KMAX - kk) >> 1;
    const int e  = (s + 2) & 7;        // alignment shift baked into B
    const int n  = lane & 15;          // B col (output x within 16-tile)
    const int kb = lane >> 4;          // k block: k'' = kb*8 + 2r + h
    const float* wrow = kern + c * (KMAX * KMAX) + dy * KMAX;
    unsigned u[4];
    #pragma unroll
    for (int r = 0; r < 4; ++r) {
        float v[2];
        #pragma unroll
        for (int h = 0; h < 2; ++h) {
            const int k = strip * 32 + kb * 8 + 2 * r + h;
            const int d = k - n - e;                   // dx - s
            v[h] = (d >= 0 && d < kk) ? wrow[d + s] : 0.0f;
        }
        u[r] = pack_f16(v[0], v[1]);
    }
    wf[(size_t)((c * KMAX + dy) * 2 + strip) * 64 + lane] =
        make_uint4(u[0], u[1], u[2], u[3]);
}

// ---------------------------- MFMA main conv -------------------------------
__global__ __launch_bounds__(256, 4)
void jagged_conv_mfma(const float* __restrict__ x,
                      const uint4* __restrict__ wf,
                      float* __restrict__ out)
{
    // XCD-aware bijective swizzle: linear id L; XCD = L&7 (round-robin
    // dispatch assumption). Give each XCD 64 complete (b,c) slices so the
    // 8 spatial blocks of one slice share that XCD's L2.
    const int L  = blockIdx.x + 2 * (blockIdx.y + 4 * blockIdx.z);
    const int X  = L & 7;
    const int g  = L >> 3;             // 0..511
    const int bc = X * 64 + (g >> 3);  // 0..511
    const int sp = g & 7;
    const int bx = sp & 1;             // 0..1  (128-wide tiles)
    const int by = sp >> 1;            // 0..3  (64-tall tiles)

    const int c  = bc & (C_CH - 1);
    const int kk = ragged_k(c);
    const int s  = (KMAX - kk) >> 1;
    const int e  = (s + 2) & 7;
    const int R  = TILE_H + kk - 1;    // staged input rows

    __shared__ __align__(16) unsigned tile[MAXR * ROWU];   // f16 pairs, 33.9 KB

    const int tid  = threadIdx.x;
    const int lane = tid & 63;
    const int w    = tid >> 6;
    const int rbase  = by * TILE_H + s - 14;       // first staged input row
    const int galign = bx * TILE_W + s - 14 - e;   // first staged col (mult of 8)
    const float* xin = x + (size_t)bc * (HW * HW);

    // ---- stage input tile+halo as packed f16 (zero outside image) ----
    // wave w handles rows w, w+4, ...; lane q<44 stages one float4 (4 cols).
    for (int r = w; r < R; r += 4) {
        const int gy = rbase + r;                  // wave-uniform
        if (lane < WQ) {
            unsigned lo = 0, hi = 0;
            if ((unsigned)gy < HW) {               // uniform branch
                const int gx = galign + 4 * lane;
                const float* row = xin + gy * HW;
                float4 v;
                if ((unsigned)gx <= (HW - 4)) {    // aligned interior float4
                    v = *(const float4*)(row + gx);
                } else {
                    v.x = ((unsigned)(gx + 0) < HW) ? row[gx + 0] : 0.0f;
                    v.y = ((unsigned)(gx + 1) < HW) ? row[gx + 1] : 0.0f;
                    v.z = ((unsigned)(gx + 2) < HW) ? row[gx + 2] : 0.0f;
                    v.w = ((unsigned)(gx + 3) < HW) ? row[gx + 3] : 0.0f;
                }
                lo = pack_f16(v.x, v.y);
                hi = pack_f16(v.z, v.w);
            }
            *(uint2*)&tile[r * ROWU + 2 * lane] = make_uint2(lo, hi);
        }
    }
    __syncthreads();

    const int ml = lane & 15;          // A row (m) and D col
    const int kb = lane >> 4;          // k block; D row = 4*kb + reg

    f32x4 a0 = {0,0,0,0}, a1 = {0,0,0,0}, a2 = {0,0,0,0}, a3 = {0,0,0,0};
    f32x4 a4 = {0,0,0,0}, a5 = {0,0,0,0}, a6 = {0,0,0,0}, a7 = {0,0,0,0};

    const __fp16* hp = (const __fp16*)tile;
    const __fp16* ap = hp + (16 * w + ml) * ROWH + 8 * kb;
    const uint4* wp = wf + (size_t)c * (KMAX * 2 * 64) + (size_t)(2 * s) * 64 + lane;

    const bool two = (kk > 17);        // block-uniform

    uint4 nb0 = wp[0];
    uint4 nb1 = two ? wp[64] : nb0;

    for (int d = 0; d < kk; ++d) {
        const uint4 b0 = nb0;
        const uint4 b1 = nb1;
        wp += 128;
        if (d + 1 < kk) {              // prefetch next dy's fragments
            nb0 = wp[0];
            if (two) nb1 = wp[64];
        }

        f16x8 F0 = *(const f16x8*)(ap +   0);
        f16x8 F1 = *(const f16x8*)(ap +  16);
        f16x8 F2 = *(const f16x8*)(ap +  32);
        f16x8 F3 = *(const f16x8*)(ap +  48);
        f16x8 F4 = *(const f16x8*)(ap +  64);
        f16x8 F5 = *(const f16x8*)(ap +  80);
        f16x8 F6 = *(const f16x8*)(ap +  96);
        f16x8 F7 = *(const f16x8*)(ap + 112);

        f16x8 B0 = uint4_as_f16x8(b0);
        a0 = __builtin_amdgcn_mfma_f32_16x16x32_f16(F0, B0, a0, 0, 0, 0);
        a1 = __builtin_amdgcn_mfma_f32_16x16x32_f16(F1, B0, a1, 0, 0, 0);
        a2 = __builtin_amdgcn_mfma_f32_16x16x32_f16(F2, B0, a2, 0, 0, 0);
        a3 = __builtin_amdgcn_mfma_f32_16x16x32_f16(F3, B0, a3, 0, 0, 0);
        a4 = __builtin_amdgcn_mfma_f32_16x16x32_f16(F4, B0, a4, 0, 0, 0);
        a5 = __builtin_amdgcn_mfma_f32_16x16x32_f16(F5, B0, a5, 0, 0, 0);
        a6 = __builtin_amdgcn_mfma_f32_16x16x32_f16(F6, B0, a6, 0, 0, 0);
        a7 = __builtin_amdgcn_mfma_f32_16x16x32_f16(F7, B0, a7, 0, 0, 0);

        if (two) {
            f16x8 F8 = *(const f16x8*)(ap + 128);
            f16x8 F9 = *(const f16x8*)(ap + 144);
            f16x8 B1 = uint4_as_f16x8(b1);
            a0 = __builtin_amdgcn_mfma_f32_16x16x32_f16(F2, B1, a0, 0, 0, 0);
            a1 = __builtin_amdgcn_mfma_f32_16x16x32_f16(F3, B1, a1, 0, 0, 0);
            a2 = __builtin_amdgcn_mfma_f32_16x16x32_f16(F4, B1, a2, 0, 0, 0);
            a3 = __builtin_amdgcn_mfma_f32_16x16x32_f16(F5, B1, a3, 0, 0, 0);
            a4 = __builtin_amdgcn_mfma_f32_16x16x32_f16(F6, B1, a4, 0, 0, 0);
            a5 = __builtin_amdgcn_mfma_f32_16x16x32_f16(F7, B1, a5, 0, 0, 0);
            a6 = __builtin_amdgcn_mfma_f32_16x16x32_f16(F8, B1, a6, 0, 0, 0);
            a7 = __builtin_amdgcn_mfma_f32_16x16x32_f16(F9, B1, a7, 0, 0, 0);
        }
        ap += ROWH;
    }

    // D layout: col = lane&15 (=ml), row = kb*4 + reg
    float* op = out + (size_t)bc * (HW * HW)
              + (size_t)(by * TILE_H + 16 * w + 4 * kb) * HW
              + bx * TILE_W + ml;
    #pragma unroll
    for (int r = 0; r < 4; ++r) {
        op[r * HW +   0] = a0[r];
        op[r * HW +  16] = a1[r];
        op[r * HW +  32] = a2[r];
        op[r * HW +  48] = a3[r];
        op[r * HW +  64] = a4[r];
        op[r * HW +  80] = a5[r];
        op[r * HW +  96] = a6[r];
        op[r * HW + 112] = a7[r];
    }
}

// ======================= fallback: fdot2 kernel (64-tile) ===================
#define FB_TILE 64
#define PAD     14
#define LDS_R   92
#define ROW_U32 52

__global__ __launch_bounds__(512)
void prepack_weights(const float* __restrict__ kern, unsigned* __restrict__ wp)
{
    const int c = blockIdx.x;
    const int tid = threadIdx.x;
    if (tid >= 29 * 16) return;
    const int dy = tid >> 4;
    const int t  = tid & 15;
    float w0 = 0.0f, w1 = 0.0f;
    if (2 * t < KMAX)     w0 = kern[c * (KMAX * KMAX) + dy * KMAX + 2 * t];
    if (2 * t + 1 < KMAX) w1 = kern[c * (KMAX * KMAX) + dy * KMAX + 2 * t + 1];
    wp[(c * KMAX + dy) * 16 + t] = pack_f16(w0, w1);
}

__global__ __launch_bounds__(256, 4)
void jagged_conv_kernel(const float* __restrict__ x,
                        const unsigned* __restrict__ wp,
                        float* __restrict__ out)
{
    const int bx = blockIdx.x;
    const int by = blockIdx.y;
    const int bc = blockIdx.z;
    const int c  = bc & (C_CH - 1);

    int kk = ragged_k(c);
    const int s  = (KMAX - kk) >> 1;
    const int t0 = s >> 1;
    const int t1 = (s + kk - 1) >> 1;

    __shared__ __align__(16) unsigned tile[LDS_R * ROW_U32];

    const int tid = threadIdx.x;
    const int gy0 = by * FB_TILE - PAD;
    const int gx0 = bx * FB_TILE - PAD;
    const float* xin = x + (size_t)bc * (HW * HW);

    for (int i = tid; i < LDS_R * ROW_U32; i += 256) {
        const int r = i / ROW_U32;
        const int p = i - r * ROW_U32;
        const int gy = gy0 + r;
        const int gx = gx0 + 2 * p;
        float a = 0.0f, b = 0.0f;
        if ((unsigned)gy < HW) {
            const float* row = xin + gy * HW;
            if ((unsigned)gx < HW)       a = row[gx];
            if ((unsigned)(gx + 1) < HW) b = row[gx + 1];
        }
        tile[i] = pack_f16(a, b);
    }
    __syncthreads();

    const int tx = tid & 7;
    const int ty = tid >> 3;

    float acc[2][8];
    #pragma unroll
    for (int j = 0; j < 2; ++j)
        #pragma unroll
        for (int p = 0; p < 8; ++p) acc[j][p] = 0.0f;

    const unsigned* wch = wp + c * (KMAX * 16);

    const int rend = s + kk + 1;
    for (int rr = s; rr < rend; ++rr) {
        const uint4* lp = (const uint4*)&tile[(ty * 2 + rr) * ROW_U32 + tx * 4];
        unsigned seg[20];
        {
            uint4 v0 = lp[0], v1 = lp[1], v2 = lp[2], v3 = lp[3], v4 = lp[4];
            seg[0]=v0.x; seg[1]=v0.y; seg[2]=v0.z; seg[3]=v0.w;
            seg[4]=v1.x; seg[5]=v1.y; seg[6]=v1.z; seg[7]=v1.w;
            seg[8]=v2.x; seg[9]=v2.y; seg[10]=v2.z; seg[11]=v2.w;
            seg[12]=v3.x; seg[13]=v3.y; seg[14]=v3.z; seg[15]=v3.w;
            seg[16]=v4.x; seg[17]=v4.y; seg[18]=v4.z; seg[19]=v4.w;
        }
        unsigned sseg[18];
        #pragma unroll
        for (int k = 0; k < 18; ++k)
            sseg[k] = __builtin_amdgcn_alignbit(seg[k + 1], seg[k], 16);

        #pragma unroll
        for (int j = 0; j < 2; ++j) {
            const int dy = rr - j;
            if (dy >= s && dy < s + kk) {
                const unsigned* wrow = wch + dy * 16;
                unsigned wv[16];
                #pragma unroll
                for (int t = 0; t < 16; ++t) wv[t] = wrow[t];
                #pragma unroll
                for (int t = 0; t < 15; ++t) {
                    if (t >= t0 && t <= t1) {
                        const half2_t wh = u32_as_h2(wv[t]);
                        acc[j][0] = __builtin_amdgcn_fdot2(u32_as_h2(seg[t + 0]), wh, acc[j][0], false);
                        acc[j][2] = __builtin_amdgcn_fdot2(u32_as_h2(seg[t + 1]), wh, acc[j][2], false);
                        acc[j][4] = __builtin_amdgcn_fdot2(u32_as_h2(seg[t + 2]), wh, acc[j][4], false);
                        acc[j][6] = __builtin_amdgcn_fdot2(u32_as_h2(seg[t + 3]), wh, acc[j][6], false);
                        acc[j][1] = __builtin_amdgcn_fdot2(u32_as_h2(sseg[t + 0]), wh, acc[j][1], false);
                        acc[j][3] = __builtin_amdgcn_fdot2(u32_as_h2(sseg[t + 1]), wh, acc[j][3], false);
                        acc[j][5] = __builtin_amdgcn_fdot2(u32_as_h2(sseg[t + 2]), wh, acc[j][5], false);
                        acc[j][7] = __builtin_amdgcn_fdot2(u32_as_h2(sseg[t + 3]), wh, acc[j][7], false);
                    }
                }
            }
        }
    }

    float* op = out + (size_t)bc * (HW * HW);
    const int ox = bx * FB_TILE + tx * 8;
    #pragma unroll
    for (int j = 0; j < 2; ++j) {
        const int oy = by * FB_TILE + ty * 2 + j;
        float4 o0 = make_float4(acc[j][0], acc[j][1], acc[j][2], acc[j][3]);
        float4 o1 = make_float4(acc[j][4], acc[j][5], acc[j][6], acc[j][7]);
        *(float4*)(op + (size_t)oy * HW + ox)     = o0;
        *(float4*)(op + (size_t)oy * HW + ox + 4) = o1;
    }
}

// ---------------------------------------------------------------------------
extern "C" void kernel_launch(void* const* d_in, const int* in_sizes, int n_in,
                              void* d_out, int out_size, void* d_ws, size_t ws_size,
                              hipStream_t stream) {
    const float* x    = (const float*)d_in[0];
    const float* kern = (const float*)d_in[1];
    float* out        = (float*)d_out;

    const size_t WF_BYTES = (size_t)C_CH * KMAX * 2 * 64 * 16;   // 7,602,176 B

    if (ws_size >= WF_BYTES) {
        uint4* wf = (uint4*)d_ws;
        prepack_frags<<<dim3(C_CH, KMAX), dim3(128), 0, stream>>>(kern, wf);
        dim3 grid(HW / TILE_W, HW / TILE_H, 4 * C_CH);           // 2 x 4 x 512
        jagged_conv_mfma<<<grid, dim3(256), 0, stream>>>(x, wf, out);
    } else {
        // fallback: fdot2 kernel (needs only 237,568 B of ws)
        unsigned* wpack = (unsigned*)d_ws;
        prepack_weights<<<dim3(C_CH), dim3(512), 0, stream>>>(kern, wpack);
        dim3 grid(HW / FB_TILE, HW / FB_TILE, 4 * C_CH);
        jagged_conv_kernel<<<grid, dim3(256), 0, stream>>>(x, wpack, out);
    }
}